// Round 1
// baseline (1540.034 us; speedup 1.0000x reference)
//
#include <hip/hip_runtime.h>
#include <cstdint>
#include <cstddef>

// Problem constants
#define BT     32768   // batch (titles)
#define NW     30      // words per title
#define VOCAB  32000
#define WD     300     // word dim
#define CH     400     // conv channels
#define AD     200     // attention dim

// ---------------------------------------------------------------------------
// Prep: Mt[i][k*200+d] = sum_c conv_w[c,i,k]*v[c,d]   (kernel folded into v)
//       bias2[d]       = sum_c conv_b[c]*v[c,d] + vb[d]
// conv_w layout: [CH, WD, 3] row-major (torch [out,in,k])
// ---------------------------------------------------------------------------
__global__ void prep_Mt_bias(const float* __restrict__ conv_w,
                             const float* __restrict__ conv_b,
                             const float* __restrict__ v,
                             const float* __restrict__ vb,
                             float* __restrict__ Mt,
                             float* __restrict__ bias2) {
  int blk = blockIdx.x;      // 0..899 -> Mt, 900 -> bias2
  int d = threadIdx.x;       // 0..199
  if (blk < 900) {
    int i = blk / 3, k = blk % 3;
    float acc = 0.f;
    #pragma unroll 4
    for (int c = 0; c < CH; ++c)
      acc += conv_w[(c * WD + i) * 3 + k] * v[c * AD + d];
    Mt[i * 600 + k * AD + d] = acc;
  } else {
    float acc = vb[d];
    #pragma unroll 4
    for (int c = 0; c < CH; ++c)
      acc += conv_b[c] * v[c * AD + d];
    bias2[d] = acc;
  }
}

// Wc[(k*300+i)*400 + c] = conv_w[c,i,k]  (transposed conv weight for final GEMM)
__global__ void prep_Wc(const float* __restrict__ conv_w, float* __restrict__ Wc) {
  int idx = blockIdx.x * 256 + threadIdx.x;
  if (idx >= 900 * CH) return;
  int c = idx % CH;
  int ki = idx / CH;
  int k = ki / WD, i = ki % WD;
  Wc[idx] = conv_w[(c * WD + i) * 3 + k];
}

// ---------------------------------------------------------------------------
// Generic fp32 SGEMM: C[M,N] = A[M,K] @ B[K,N] (+ bias_m[r]*bias_n[c] rank-1)
// 128x128 tile, BK=8, 256 threads, 8x8 per thread. M%128==0, N%8==0, K%4==0.
// ---------------------------------------------------------------------------
__global__ __launch_bounds__(256) void sgemm128(
    const float* __restrict__ A, const float* __restrict__ Bm,
    float* __restrict__ C, int M, int N, int K,
    const float* __restrict__ bias_m, const float* __restrict__ bias_n) {
  __shared__ float As[8][128];
  __shared__ float Bs[8][128];
  int tid = threadIdx.x;
  int row0 = blockIdx.y * 128, col0 = blockIdx.x * 128;
  int tx = tid & 15, ty = tid >> 4;
  int arow = tid >> 1, akq = (tid & 1) * 4;
  int brow = tid >> 5, bcol = (tid & 31) * 4;

  float acc[8][8];
  #pragma unroll
  for (int i = 0; i < 8; ++i)
    #pragma unroll
    for (int j = 0; j < 8; ++j) acc[i][j] = 0.f;

  for (int k0 = 0; k0 < K; k0 += 8) {
    float4 av = make_float4(0.f, 0.f, 0.f, 0.f);
    int ar = row0 + arow, ak = k0 + akq;
    if (ar < M && ak < K) av = *(const float4*)(A + (size_t)ar * K + ak);
    As[akq + 0][arow] = av.x;
    As[akq + 1][arow] = av.y;
    As[akq + 2][arow] = av.z;
    As[akq + 3][arow] = av.w;

    float4 bv = make_float4(0.f, 0.f, 0.f, 0.f);
    int bk = k0 + brow, bc = col0 + bcol;
    if (bk < K && bc < N) bv = *(const float4*)(Bm + (size_t)bk * N + bc);
    *(float4*)&Bs[brow][bcol] = bv;
    __syncthreads();

    #pragma unroll
    for (int kk = 0; kk < 8; ++kk) {
      float af[8], bf[8];
      *(float4*)&af[0] = *(const float4*)&As[kk][ty * 8];
      *(float4*)&af[4] = *(const float4*)&As[kk][ty * 8 + 4];
      *(float4*)&bf[0] = *(const float4*)&Bs[kk][tx * 8];
      *(float4*)&bf[4] = *(const float4*)&Bs[kk][tx * 8 + 4];
      #pragma unroll
      for (int i = 0; i < 8; ++i)
        #pragma unroll
        for (int j = 0; j < 8; ++j)
          acc[i][j] = fmaf(af[i], bf[j], acc[i][j]);
    }
    __syncthreads();
  }

  #pragma unroll
  for (int i = 0; i < 8; ++i) {
    int r = row0 + ty * 8 + i;
    if (r >= M) continue;
    int c = col0 + tx * 8;
    if (c >= N) continue;
    float bm = bias_m ? bias_m[r] : 0.f;
    float out[8];
    #pragma unroll
    for (int j = 0; j < 8; ++j) {
      float val = acc[i][j];
      if (bias_m) val += bm * bias_n[c + j];
      out[j] = val;
    }
    *(float4*)(C + (size_t)r * N + c) = *(float4*)&out[0];
    *(float4*)(C + (size_t)r * N + c + 4) = *(float4*)&out[4];
  }
}

// ---------------------------------------------------------------------------
// Scores: a[n*BT + b] = sum_d tanh(E3[t_{n-1},0,d] + E3[t_n,1,d] + E3[t_{n+1},2,d]
//                                  + bias2[d]) * q[d]
// One wave per (b,n). Stored [N][B] for coalesced softmax columns.
// ---------------------------------------------------------------------------
__global__ void scores_kernel(const int* __restrict__ tok,
                              const float* __restrict__ E3,
                              const float* __restrict__ bias2,
                              const float* __restrict__ q,
                              float* __restrict__ a_out) {
  int gtid = blockIdx.x * 256 + threadIdx.x;
  int wid = gtid >> 6;
  int lane = threadIdx.x & 63;
  if (wid >= BT * NW) return;
  int b = wid / NW, n = wid % NW;
  const int* tb = tok + b * NW;
  int t0 = (n >= 1) ? tb[n - 1] : -1;   // conv tap k=0 uses input n-1
  int t1 = tb[n];                       // k=1 uses n
  int t2 = (n <= NW - 2) ? tb[n + 1] : -1;  // k=2 uses n+1
  float partial = 0.f;
  #pragma unroll
  for (int j = 0; j < 4; ++j) {
    int d = j * 64 + lane;
    if (d < AD) {
      float s = bias2[d];
      if (t0 >= 0) s += E3[(size_t)t0 * 600 + d];
      s += E3[(size_t)t1 * 600 + 200 + d];
      if (t2 >= 0) s += E3[(size_t)t2 * 600 + 400 + d];
      partial += tanhf(s) * q[d];
    }
  }
  #pragma unroll
  for (int off = 32; off > 0; off >>= 1) partial += __shfl_down(partial, off, 64);
  if (lane == 0) a_out[(size_t)n * BT + b] = partial;
}

// ---------------------------------------------------------------------------
// Softmax over the BATCH axis: per column n, max & 1/sum over 32768 entries.
// ---------------------------------------------------------------------------
__global__ void softmax_stats(const float* __restrict__ a,
                              float* __restrict__ rmax, float* __restrict__ rinv) {
  int n = blockIdx.x;           // 0..29
  int tid = threadIdx.x;        // 1024
  const float* col = a + (size_t)n * BT;
  float vals[32];
  float vmax = -INFINITY;
  #pragma unroll
  for (int j = 0; j < 32; ++j) {
    vals[j] = col[tid + j * 1024];
    vmax = fmaxf(vmax, vals[j]);
  }
  __shared__ float redm[16];
  __shared__ float reds[16];
  int wid = tid >> 6, lane = tid & 63;
  #pragma unroll
  for (int off = 32; off > 0; off >>= 1) vmax = fmaxf(vmax, __shfl_down(vmax, off, 64));
  if (lane == 0) redm[wid] = vmax;
  __syncthreads();
  if (tid == 0) {
    float m = redm[0];
    for (int i = 1; i < 16; ++i) m = fmaxf(m, redm[i]);
    redm[0] = m;
  }
  __syncthreads();
  float m = redm[0];
  float s = 0.f;
  #pragma unroll
  for (int j = 0; j < 32; ++j) s += expf(vals[j] - m);
  #pragma unroll
  for (int off = 32; off > 0; off >>= 1) s += __shfl_down(s, off, 64);
  if (lane == 0) reds[wid] = s;
  __syncthreads();
  if (tid == 0) {
    float t = 0.f;
    for (int i = 0; i < 16; ++i) t += reds[i];
    rmax[n] = m;
    rinv[n] = 1.0f / t;
  }
}

// ---------------------------------------------------------------------------
// U[b, k*300+i] = sum_m alpha[b, m-k+1] * emb[tok[b,m], i]   (alpha OOB -> 0)
// Salpha[b] = sum_n alpha[b,n]
// One block (256 threads) per title.
// ---------------------------------------------------------------------------
__global__ void build_U(const int* __restrict__ tok, const float* __restrict__ emb,
                        const float* __restrict__ a, const float* __restrict__ rmax,
                        const float* __restrict__ rinv, float* __restrict__ U,
                        float* __restrict__ Salpha) {
  int b = blockIdx.x;
  int tid = threadIdx.x;  // 256
  __shared__ float alpha[NW];
  __shared__ int ltok[NW];
  if (tid < NW) {
    ltok[tid] = tok[b * NW + tid];
    alpha[tid] = expf(a[(size_t)tid * BT + b] - rmax[tid]) * rinv[tid];
  }
  __syncthreads();
  if (tid == 0) {
    float s = 0.f;
    #pragma unroll
    for (int n = 0; n < NW; ++n) s += alpha[n];
    Salpha[b] = s;
  }
  float a0 = 0.f, a1 = 0.f, a2 = 0.f;    // i = tid
  float b0 = 0.f, b1 = 0.f, b2 = 0.f;    // i = 256+tid (if < 300)
  int i2 = 256 + tid;
  #pragma unroll 2
  for (int m = 0; m < NW; ++m) {
    int t = ltok[m];
    float w0 = (m + 1 < NW) ? alpha[m + 1] : 0.f;  // k=0 -> n=m+1
    float w1 = alpha[m];                           // k=1 -> n=m
    float w2 = (m >= 1) ? alpha[m - 1] : 0.f;      // k=2 -> n=m-1
    const float* er = emb + (size_t)t * WD;
    float x = er[tid];
    a0 = fmaf(w0, x, a0); a1 = fmaf(w1, x, a1); a2 = fmaf(w2, x, a2);
    if (i2 < WD) {
      float y = er[i2];
      b0 = fmaf(w0, y, b0); b1 = fmaf(w1, y, b1); b2 = fmaf(w2, y, b2);
    }
  }
  float* Ub = U + (size_t)b * 900;
  Ub[tid] = a0; Ub[300 + tid] = a1; Ub[600 + tid] = a2;
  if (i2 < WD) { Ub[i2] = b0; Ub[300 + i2] = b1; Ub[600 + i2] = b2; }
}

// ---------------------------------------------------------------------------
extern "C" void kernel_launch(void* const* d_in, const int* in_sizes, int n_in,
                              void* d_out, int out_size, void* d_ws, size_t ws_size,
                              hipStream_t stream) {
  const int*   tok    = (const int*)d_in[0];
  const float* emb    = (const float*)d_in[1];
  const float* conv_w = (const float*)d_in[2];
  const float* conv_b = (const float*)d_in[3];
  const float* v      = (const float*)d_in[4];
  const float* vb     = (const float*)d_in[5];
  const float* q      = (const float*)d_in[6];
  float* out = (float*)d_out;

  // Workspace layout (floats). Total ~31.05M floats = ~124 MB.
  float* w      = (float*)d_ws;
  float* Wc     = w;                  // 360000
  float* Mt     = Wc + 360000;        // 180000
  float* bias2  = Mt + 180000;        // 200
  float* rmax   = bias2 + 200;        // 32 (padded)
  float* rinv   = rmax + 32;          // 32 (padded)
  float* Salpha = rinv + 32;          // 32768
  float* a_ws   = Salpha + BT;        // 983040  ([N][B] layout)
  float* big    = a_ws + (size_t)NW * BT;  // E3 (19.2M floats) then U (29.49M floats)
  float* E3 = big;
  float* U  = big;   // aliases E3 — E3 is dead after scores_kernel

  // 1. Fold conv weight into v (Mt) + bias2; transpose conv weight (Wc)
  hipLaunchKernelGGL(prep_Mt_bias, dim3(901), dim3(200), 0, stream,
                     conv_w, conv_b, v, vb, Mt, bias2);
  hipLaunchKernelGGL(prep_Wc, dim3((900 * CH + 255) / 256), dim3(256), 0, stream,
                     conv_w, Wc);
  // 2. E3[32000,600] = emb[32000,300] @ Mt[300,600]
  hipLaunchKernelGGL(sgemm128, dim3(5, 250), dim3(256), 0, stream,
                     emb, Mt, E3, VOCAB, 600, WD,
                     (const float*)nullptr, (const float*)nullptr);
  // 3. Attention scores a[n,b]
  hipLaunchKernelGGL(scores_kernel, dim3((BT * NW) / 4), dim3(256), 0, stream,
                     tok, E3, bias2, q, a_ws);
  // 4. Softmax-over-batch stats per column
  hipLaunchKernelGGL(softmax_stats, dim3(NW), dim3(1024), 0, stream,
                     a_ws, rmax, rinv);
  // 5. Alpha-weighted embedding sums U[32768,900] (+ Salpha)
  hipLaunchKernelGGL(build_U, dim3(BT), dim3(256), 0, stream,
                     tok, emb, a_ws, rmax, rinv, U, Salpha);
  // 6. e[32768,400] = U @ Wc + Salpha ⊗ conv_b
  hipLaunchKernelGGL(sgemm128, dim3(4, 256), dim3(256), 0, stream,
                     U, Wc, out, BT, CH, 900, Salpha, conv_b);
}

// Round 2
// 1507.760 us; speedup vs baseline: 1.0214x; 1.0214x over previous
//
#include <hip/hip_runtime.h>
#include <cstdint>
#include <cstddef>

// Problem constants
#define BT     32768   // batch (titles)
#define NW     30      // words per title
#define VOCAB  32000
#define WD     300     // word dim
#define CH     400     // conv channels
#define AD     200     // attention dim

// Fast tanh via native v_exp_f32: tanh(x) = 1 - 2/(exp(2x)+1).
// Saturates correctly for |x| large (exp->inf -> 1; exp->0 -> -1).
// Abs error ~1e-7 — far under the 5.4e-4 output threshold.
__device__ __forceinline__ float tanh_fast(float x) {
  float e = __expf(2.0f * x);
  return 1.0f - __fdividef(2.0f, e + 1.0f);
}

// ---------------------------------------------------------------------------
// Prep: Mt[i][k*200+d] = sum_c conv_w[c,i,k]*v[c,d]   (kernel folded into v)
//       bias2[d]       = sum_c conv_b[c]*v[c,d] + vb[d]
// conv_w layout: [CH, WD, 3] row-major (torch [out,in,k])
// ---------------------------------------------------------------------------
__global__ void prep_Mt_bias(const float* __restrict__ conv_w,
                             const float* __restrict__ conv_b,
                             const float* __restrict__ v,
                             const float* __restrict__ vb,
                             float* __restrict__ Mt,
                             float* __restrict__ bias2) {
  int blk = blockIdx.x;      // 0..899 -> Mt, 900 -> bias2
  int d = threadIdx.x;       // 0..199
  if (blk < 900) {
    int i = blk / 3, k = blk % 3;
    float acc = 0.f;
    #pragma unroll 4
    for (int c = 0; c < CH; ++c)
      acc += conv_w[(c * WD + i) * 3 + k] * v[c * AD + d];
    Mt[i * 600 + k * AD + d] = acc;
  } else {
    float acc = vb[d];
    #pragma unroll 4
    for (int c = 0; c < CH; ++c)
      acc += conv_b[c] * v[c * AD + d];
    bias2[d] = acc;
  }
}

// Wc[(k*300+i)*400 + c] = conv_w[c,i,k]  (transposed conv weight for final GEMM)
__global__ void prep_Wc(const float* __restrict__ conv_w, float* __restrict__ Wc) {
  int idx = blockIdx.x * 256 + threadIdx.x;
  if (idx >= 900 * CH) return;
  int c = idx % CH;
  int ki = idx / CH;
  int k = ki / WD, i = ki % WD;
  Wc[idx] = conv_w[(c * WD + i) * 3 + k];
}

// ---------------------------------------------------------------------------
// Generic fp32 SGEMM: C[M,N] = A[M,K] @ B[K,N] (+ bias_m[r]*bias_n[c] rank-1)
// 128x128 tile, BK=8, 256 threads, 8x8 per thread.
// ---------------------------------------------------------------------------
__global__ __launch_bounds__(256) void sgemm128(
    const float* __restrict__ A, const float* __restrict__ Bm,
    float* __restrict__ C, int M, int N, int K,
    const float* __restrict__ bias_m, const float* __restrict__ bias_n) {
  __shared__ float As[8][128];
  __shared__ float Bs[8][128];
  int tid = threadIdx.x;
  int row0 = blockIdx.y * 128, col0 = blockIdx.x * 128;
  int tx = tid & 15, ty = tid >> 4;
  int arow = tid >> 1, akq = (tid & 1) * 4;
  int brow = tid >> 5, bcol = (tid & 31) * 4;

  float acc[8][8];
  #pragma unroll
  for (int i = 0; i < 8; ++i)
    #pragma unroll
    for (int j = 0; j < 8; ++j) acc[i][j] = 0.f;

  for (int k0 = 0; k0 < K; k0 += 8) {
    float4 av = make_float4(0.f, 0.f, 0.f, 0.f);
    int ar = row0 + arow, ak = k0 + akq;
    if (ar < M && ak < K) av = *(const float4*)(A + (size_t)ar * K + ak);
    As[akq + 0][arow] = av.x;
    As[akq + 1][arow] = av.y;
    As[akq + 2][arow] = av.z;
    As[akq + 3][arow] = av.w;

    float4 bv = make_float4(0.f, 0.f, 0.f, 0.f);
    int bk = k0 + brow, bc = col0 + bcol;
    if (bk < K && bc < N) bv = *(const float4*)(Bm + (size_t)bk * N + bc);
    *(float4*)&Bs[brow][bcol] = bv;
    __syncthreads();

    #pragma unroll
    for (int kk = 0; kk < 8; ++kk) {
      float af[8], bf[8];
      *(float4*)&af[0] = *(const float4*)&As[kk][ty * 8];
      *(float4*)&af[4] = *(const float4*)&As[kk][ty * 8 + 4];
      *(float4*)&bf[0] = *(const float4*)&Bs[kk][tx * 8];
      *(float4*)&bf[4] = *(const float4*)&Bs[kk][tx * 8 + 4];
      #pragma unroll
      for (int i = 0; i < 8; ++i)
        #pragma unroll
        for (int j = 0; j < 8; ++j)
          acc[i][j] = fmaf(af[i], bf[j], acc[i][j]);
    }
    __syncthreads();
  }

  #pragma unroll
  for (int i = 0; i < 8; ++i) {
    int r = row0 + ty * 8 + i;
    if (r >= M) continue;
    int c = col0 + tx * 8;
    if (c >= N) continue;
    float bm = bias_m ? bias_m[r] : 0.f;
    float out[8];
    #pragma unroll
    for (int j = 0; j < 8; ++j) {
      float val = acc[i][j];
      if (bias_m) val += bm * bias_n[c + j];
      out[j] = val;
    }
    *(float4*)(C + (size_t)r * N + c) = *(float4*)&out[0];
    *(float4*)(C + (size_t)r * N + c + 4) = *(float4*)&out[4];
  }
}

// ---------------------------------------------------------------------------
// Scores: a[n*BT + b] = sum_d tanh(E3[t_{n-1},0,d] + E3[t_n,1,d] + E3[t_{n+1},2,d]
//                                  + bias2[d]) * q[d]
// One wave per (b,n). Stored [N][B] for coalesced softmax columns.
// ---------------------------------------------------------------------------
__global__ void scores_kernel(const int* __restrict__ tok,
                              const float* __restrict__ E3,
                              const float* __restrict__ bias2,
                              const float* __restrict__ q,
                              float* __restrict__ a_out) {
  int gtid = blockIdx.x * 256 + threadIdx.x;
  int wid = gtid >> 6;
  int lane = threadIdx.x & 63;
  if (wid >= BT * NW) return;
  int b = wid / NW, n = wid % NW;
  const int* tb = tok + b * NW;
  int t0 = (n >= 1) ? tb[n - 1] : -1;   // conv tap k=0 uses input n-1
  int t1 = tb[n];                       // k=1 uses n
  int t2 = (n <= NW - 2) ? tb[n + 1] : -1;  // k=2 uses n+1
  float partial = 0.f;
  #pragma unroll
  for (int j = 0; j < 4; ++j) {
    int d = j * 64 + lane;
    if (d < AD) {
      float s = bias2[d];
      if (t0 >= 0) s += E3[(size_t)t0 * 600 + d];
      s += E3[(size_t)t1 * 600 + 200 + d];
      if (t2 >= 0) s += E3[(size_t)t2 * 600 + 400 + d];
      partial += tanh_fast(s) * q[d];
    }
  }
  #pragma unroll
  for (int off = 32; off > 0; off >>= 1) partial += __shfl_down(partial, off, 64);
  if (lane == 0) a_out[(size_t)n * BT + b] = partial;
}

// ---------------------------------------------------------------------------
// Softmax over the BATCH axis: per column n, max & 1/sum over 32768 entries.
// ---------------------------------------------------------------------------
__global__ void softmax_stats(const float* __restrict__ a,
                              float* __restrict__ rmax, float* __restrict__ rinv) {
  int n = blockIdx.x;           // 0..29
  int tid = threadIdx.x;        // 1024
  const float* col = a + (size_t)n * BT;
  float vals[32];
  float vmax = -INFINITY;
  #pragma unroll
  for (int j = 0; j < 32; ++j) {
    vals[j] = col[tid + j * 1024];
    vmax = fmaxf(vmax, vals[j]);
  }
  __shared__ float redm[16];
  __shared__ float reds[16];
  int wid = tid >> 6, lane = tid & 63;
  #pragma unroll
  for (int off = 32; off > 0; off >>= 1) vmax = fmaxf(vmax, __shfl_down(vmax, off, 64));
  if (lane == 0) redm[wid] = vmax;
  __syncthreads();
  if (tid == 0) {
    float m = redm[0];
    for (int i = 1; i < 16; ++i) m = fmaxf(m, redm[i]);
    redm[0] = m;
  }
  __syncthreads();
  float m = redm[0];
  float s = 0.f;
  #pragma unroll
  for (int j = 0; j < 32; ++j) s += __expf(vals[j] - m);
  #pragma unroll
  for (int off = 32; off > 0; off >>= 1) s += __shfl_down(s, off, 64);
  if (lane == 0) reds[wid] = s;
  __syncthreads();
  if (tid == 0) {
    float t = 0.f;
    for (int i = 0; i < 16; ++i) t += reds[i];
    rmax[n] = m;
    rinv[n] = 1.0f / t;
  }
}

// ---------------------------------------------------------------------------
// U[b, k*300+i] = sum_m alpha[b, m-k+1] * emb[tok[b,m], i]   (alpha OOB -> 0)
// Salpha[b] = sum_n alpha[b,n]
// One block (256 threads) per title.
// ---------------------------------------------------------------------------
__global__ void build_U(const int* __restrict__ tok, const float* __restrict__ emb,
                        const float* __restrict__ a, const float* __restrict__ rmax,
                        const float* __restrict__ rinv, float* __restrict__ U,
                        float* __restrict__ Salpha) {
  int b = blockIdx.x;
  int tid = threadIdx.x;  // 256
  __shared__ float alpha[NW];
  __shared__ int ltok[NW];
  if (tid < NW) {
    ltok[tid] = tok[b * NW + tid];
    alpha[tid] = __expf(a[(size_t)tid * BT + b] - rmax[tid]) * rinv[tid];
  }
  __syncthreads();
  if (tid == 0) {
    float s = 0.f;
    #pragma unroll
    for (int n = 0; n < NW; ++n) s += alpha[n];
    Salpha[b] = s;
  }
  float a0 = 0.f, a1 = 0.f, a2 = 0.f;    // i = tid
  float b0 = 0.f, b1 = 0.f, b2 = 0.f;    // i = 256+tid (if < 300)
  int i2 = 256 + tid;
  #pragma unroll 2
  for (int m = 0; m < NW; ++m) {
    int t = ltok[m];
    float w0 = (m + 1 < NW) ? alpha[m + 1] : 0.f;  // k=0 -> n=m+1
    float w1 = alpha[m];                           // k=1 -> n=m
    float w2 = (m >= 1) ? alpha[m - 1] : 0.f;      // k=2 -> n=m-1
    const float* er = emb + (size_t)t * WD;
    float x = er[tid];
    a0 = fmaf(w0, x, a0); a1 = fmaf(w1, x, a1); a2 = fmaf(w2, x, a2);
    if (i2 < WD) {
      float y = er[i2];
      b0 = fmaf(w0, y, b0); b1 = fmaf(w1, y, b1); b2 = fmaf(w2, y, b2);
    }
  }
  float* Ub = U + (size_t)b * 900;
  Ub[tid] = a0; Ub[300 + tid] = a1; Ub[600 + tid] = a2;
  if (i2 < WD) { Ub[i2] = b0; Ub[300 + i2] = b1; Ub[600 + i2] = b2; }
}

// ---------------------------------------------------------------------------
extern "C" void kernel_launch(void* const* d_in, const int* in_sizes, int n_in,
                              void* d_out, int out_size, void* d_ws, size_t ws_size,
                              hipStream_t stream) {
  const int*   tok    = (const int*)d_in[0];
  const float* emb    = (const float*)d_in[1];
  const float* conv_w = (const float*)d_in[2];
  const float* conv_b = (const float*)d_in[3];
  const float* v      = (const float*)d_in[4];
  const float* vb     = (const float*)d_in[5];
  const float* q      = (const float*)d_in[6];
  float* out = (float*)d_out;

  // Workspace layout (floats). Total ~31.05M floats = ~124 MB.
  float* w      = (float*)d_ws;
  float* Wc     = w;                  // 360000
  float* Mt     = Wc + 360000;        // 180000
  float* bias2  = Mt + 180000;        // 200
  float* rmax   = bias2 + 200;        // 32 (padded)
  float* rinv   = rmax + 32;          // 32 (padded)
  float* Salpha = rinv + 32;          // 32768
  float* a_ws   = Salpha + BT;        // 983040  ([N][B] layout)
  float* big    = a_ws + (size_t)NW * BT;  // E3 (19.2M floats) then U (29.49M floats)
  float* E3 = big;
  float* U  = big;   // aliases E3 — E3 is dead after scores_kernel

  // 1. Fold conv weight into v (Mt) + bias2; transpose conv weight (Wc)
  hipLaunchKernelGGL(prep_Mt_bias, dim3(901), dim3(200), 0, stream,
                     conv_w, conv_b, v, vb, Mt, bias2);
  hipLaunchKernelGGL(prep_Wc, dim3((900 * CH + 255) / 256), dim3(256), 0, stream,
                     conv_w, Wc);
  // 2. E3[32000,600] = emb[32000,300] @ Mt[300,600]
  hipLaunchKernelGGL(sgemm128, dim3(5, 250), dim3(256), 0, stream,
                     emb, Mt, E3, VOCAB, 600, WD,
                     (const float*)nullptr, (const float*)nullptr);
  // 3. Attention scores a[n,b]
  hipLaunchKernelGGL(scores_kernel, dim3((BT * NW) / 4), dim3(256), 0, stream,
                     tok, E3, bias2, q, a_ws);
  // 4. Softmax-over-batch stats per column
  hipLaunchKernelGGL(softmax_stats, dim3(NW), dim3(1024), 0, stream,
                     a_ws, rmax, rinv);
  // 5. Alpha-weighted embedding sums U[32768,900] (+ Salpha)
  hipLaunchKernelGGL(build_U, dim3(BT), dim3(256), 0, stream,
                     tok, emb, a_ws, rmax, rinv, U, Salpha);
  // 6. e[32768,400] = U @ Wc + Salpha ⊗ conv_b
  hipLaunchKernelGGL(sgemm128, dim3(4, 256), dim3(256), 0, stream,
                     U, Wc, out, BT, CH, 900, Salpha, conv_b);
}

// Round 3
// 665.174 us; speedup vs baseline: 2.3152x; 2.2667x over previous
//
#include <hip/hip_runtime.h>
#include <cstdint>
#include <cstddef>

// Problem constants
#define BT     32768   // batch (titles)
#define NW     30      // words per title
#define VOCAB  32000
#define WD     300     // word dim
#define CH     400     // conv channels
#define AD     200     // attention dim

// Padded bf16 layouts
#define EMB_LD   320   // emb_bf16 [VOCAB][320]  (300 + pad)
#define E3_LD    640   // E3 bf16 [VOCAB][640]   (600 + pad)
#define U_LD     928   // U bf16 [BT][928]       (900 + pad)
#define WCT_ROWS 512   // WcT bf16 [512][928]    (400 + pad rows)

typedef __attribute__((ext_vector_type(8))) short bf16x8;
typedef __attribute__((ext_vector_type(4))) float f32x4;

__device__ __forceinline__ float bf2f(unsigned short u) {
  union { unsigned int i; float f; } x; x.i = ((unsigned int)u) << 16; return x.f;
}
__device__ __forceinline__ unsigned short f2bf(float f) {
  union { float f; unsigned int i; } x; x.f = f;
  unsigned int r = x.i + 0x7FFFu + ((x.i >> 16) & 1u);   // RNE
  return (unsigned short)(r >> 16);
}
__device__ __forceinline__ unsigned int pack2bf(float a, float b) {
  return (unsigned int)f2bf(a) | ((unsigned int)f2bf(b) << 16);
}

// Fast tanh via native v_exp_f32: tanh(x) = 1 - 2/(exp(2x)+1). Saturates correctly.
__device__ __forceinline__ float tanh_fast(float x) {
  float e = __expf(2.0f * x);
  return 1.0f - __fdividef(2.0f, e + 1.0f);
}

// ---------------------------------------------------------------------------
// Prep: Mt[i][k*200+d] = sum_c conv_w[c,i,k]*v[c,d]  (fp32, [300][600])
//       bias2[d]       = sum_c conv_b[c]*v[c,d] + vb[d]
// ---------------------------------------------------------------------------
__global__ void prep_Mt_bias(const float* __restrict__ conv_w,
                             const float* __restrict__ conv_b,
                             const float* __restrict__ v,
                             const float* __restrict__ vb,
                             float* __restrict__ Mt,
                             float* __restrict__ bias2) {
  int blk = blockIdx.x;      // 0..899 -> Mt, 900 -> bias2
  int d = threadIdx.x;       // 0..199
  if (blk < 900) {
    int i = blk / 3, k = blk % 3;
    float acc = 0.f;
    #pragma unroll 4
    for (int c = 0; c < CH; ++c)
      acc += conv_w[(c * WD + i) * 3 + k] * v[c * AD + d];
    Mt[i * 600 + k * AD + d] = acc;
  } else {
    float acc = vb[d];
    #pragma unroll 4
    for (int c = 0; c < CH; ++c)
      acc += conv_b[c] * v[c * AD + d];
    bias2[d] = acc;
  }
}

// MtT[n][i] = bf16(Mt[i][n]) for n<600,i<300 else 0.  [E3_LD][EMB_LD]
__global__ void conv_MtT(const float* __restrict__ Mt, unsigned short* __restrict__ MtT) {
  int n = blockIdx.x;    // 640
  int i = threadIdx.x;   // 320
  float val = (n < 600 && i < WD) ? Mt[i * 600 + n] : 0.f;
  MtT[n * EMB_LD + i] = f2bf(val);
}

// WcT[c][kk] = bf16(conv_w[c, i, k]), kk = k*300+i; zero-padded. [512][928]
__global__ void prep_WcT(const float* __restrict__ conv_w, unsigned short* __restrict__ WcT) {
  int c = blockIdx.x;    // 512
  for (int kk = threadIdx.x; kk < U_LD; kk += 256) {
    float val = 0.f;
    if (c < CH && kk < 900) {
      int k = kk / WD, i = kk - k * WD;
      val = conv_w[(c * WD + i) * 3 + k];
    }
    WcT[(size_t)c * U_LD + kk] = f2bf(val);
  }
}

// emb -> bf16, zero-padded cols. [VOCAB][320]
__global__ void prep_emb_bf16(const float* __restrict__ emb, unsigned short* __restrict__ embb) {
  int idx = blockIdx.x * 256 + threadIdx.x;
  if (idx >= VOCAB * EMB_LD) return;
  int r = idx / EMB_LD, c = idx - r * EMB_LD;
  embb[idx] = (c < WD) ? f2bf(emb[(size_t)r * WD + c]) : (unsigned short)0;
}

// ---------------------------------------------------------------------------
// bf16 MFMA GEMM: C[M,N] = A[M,K] @ Bt[N,K]^T. 128x128 tile, K-step 32,
// 4 waves each computing 4x4 of 16x16x32 tiles. M%128==0, K%32==0,
// Bt has >=gridDim.x*128 rows (zero-padded). OUT_BF16: store bf16, no guard.
// else: fp32 store with col<N guard + rank-1 bias_m[r]*bias_n[c].
// ---------------------------------------------------------------------------
template<bool OUT_BF16>
__global__ __launch_bounds__(256) void gemm_mfma(
    const unsigned short* __restrict__ A, int lda,
    const unsigned short* __restrict__ Bt, int ldb,
    void* __restrict__ Cp, int ldc, int N, int K,
    const float* __restrict__ bias_m, const float* __restrict__ bias_n) {
  __shared__ unsigned short As[128][40];   // +8 pad
  __shared__ unsigned short Bs[128][40];
  int tid = threadIdx.x;
  int lane = tid & 63, wave = tid >> 6;
  int row0 = blockIdx.y * 128, col0 = blockIdx.x * 128;
  int wm = (wave & 1) * 64, wn = (wave >> 1) * 64;
  int lr = lane & 15, quad = lane >> 4;

  f32x4 acc[4][4];
  #pragma unroll
  for (int i = 0; i < 4; ++i)
    #pragma unroll
    for (int j = 0; j < 4; ++j) acc[i][j] = (f32x4){0.f, 0.f, 0.f, 0.f};

  // staging: 512 chunks of 8 bf16 per tile; thread handles chunks tid, tid+256
  int r0 = tid >> 2, ko0 = (tid & 3) * 8;
  int r1 = (tid + 256) >> 2, ko1 = ((tid + 256) & 3) * 8;

  for (int k0 = 0; k0 < K; k0 += 32) {
    float4 av0 = *(const float4*)(A + (size_t)(row0 + r0) * lda + k0 + ko0);
    float4 av1 = *(const float4*)(A + (size_t)(row0 + r1) * lda + k0 + ko1);
    float4 bv0 = *(const float4*)(Bt + (size_t)(col0 + r0) * ldb + k0 + ko0);
    float4 bv1 = *(const float4*)(Bt + (size_t)(col0 + r1) * ldb + k0 + ko1);
    __syncthreads();
    *(float4*)&As[r0][ko0] = av0;
    *(float4*)&As[r1][ko1] = av1;
    *(float4*)&Bs[r0][ko0] = bv0;
    *(float4*)&Bs[r1][ko1] = bv1;
    __syncthreads();

    bf16x8 af[4], bfr[4];
    #pragma unroll
    for (int mi = 0; mi < 4; ++mi)
      af[mi] = *(const bf16x8*)&As[wm + mi * 16 + lr][quad * 8];
    #pragma unroll
    for (int ni = 0; ni < 4; ++ni)
      bfr[ni] = *(const bf16x8*)&Bs[wn + ni * 16 + lr][quad * 8];
    #pragma unroll
    for (int mi = 0; mi < 4; ++mi)
      #pragma unroll
      for (int ni = 0; ni < 4; ++ni)
        acc[mi][ni] = __builtin_amdgcn_mfma_f32_16x16x32_bf16(
            af[mi], bfr[ni], acc[mi][ni], 0, 0, 0);
  }

  // Epilogue. C/D layout: col = lane&15, row = quad*4 + reg.
  if (OUT_BF16) {
    unsigned short* C = (unsigned short*)Cp;
    #pragma unroll
    for (int mi = 0; mi < 4; ++mi)
      #pragma unroll
      for (int ni = 0; ni < 4; ++ni) {
        int c = col0 + wn + ni * 16 + lr;
        #pragma unroll
        for (int reg = 0; reg < 4; ++reg) {
          int r = row0 + wm + mi * 16 + quad * 4 + reg;
          C[(size_t)r * ldc + c] = f2bf(acc[mi][ni][reg]);
        }
      }
  } else {
    float* C = (float*)Cp;
    #pragma unroll
    for (int mi = 0; mi < 4; ++mi)
      #pragma unroll
      for (int ni = 0; ni < 4; ++ni) {
        int c = col0 + wn + ni * 16 + lr;
        if (c < N) {
          float bn = bias_n[c];
          #pragma unroll
          for (int reg = 0; reg < 4; ++reg) {
            int r = row0 + wm + mi * 16 + quad * 4 + reg;
            C[(size_t)r * ldc + c] = acc[mi][ni][reg] + bias_m[r] * bn;
          }
        }
      }
  }
}

// ---------------------------------------------------------------------------
// Scores: a[n*BT+b] = sum_d tanh(E3[t0,d] + E3[t1,200+d] + E3[t2,400+d] + bias2[d]) * q[d]
// One wave per (b,n); lanes 0..49 each own 4 consecutive d (uint2 bf16 loads).
// ---------------------------------------------------------------------------
__global__ __launch_bounds__(256) void scores_kernel(
    const int* __restrict__ tok, const unsigned short* __restrict__ E3,
    const float* __restrict__ bias2, const float* __restrict__ q,
    float* __restrict__ a_out) {
  int gtid = blockIdx.x * 256 + threadIdx.x;
  int wid = gtid >> 6, lane = threadIdx.x & 63;
  int b = wid / NW, n = wid - b * NW;
  const int* tb = tok + b * NW;
  int t1 = tb[n];
  int t0 = (n >= 1) ? tb[n - 1] : -1;
  int t2 = (n < NW - 1) ? tb[n + 1] : -1;
  float part = 0.f;
  if (lane < 50) {
    int d = lane * 4;
    float4 s = *(const float4*)(bias2 + d);
    float4 qq = *(const float4*)(q + d);
    if (t0 >= 0) {
      uint2 u = *(const uint2*)(E3 + (size_t)t0 * E3_LD + d);
      s.x += bf2f((unsigned short)u.x); s.y += bf2f((unsigned short)(u.x >> 16));
      s.z += bf2f((unsigned short)u.y); s.w += bf2f((unsigned short)(u.y >> 16));
    }
    {
      uint2 u = *(const uint2*)(E3 + (size_t)t1 * E3_LD + 200 + d);
      s.x += bf2f((unsigned short)u.x); s.y += bf2f((unsigned short)(u.x >> 16));
      s.z += bf2f((unsigned short)u.y); s.w += bf2f((unsigned short)(u.y >> 16));
    }
    if (t2 >= 0) {
      uint2 u = *(const uint2*)(E3 + (size_t)t2 * E3_LD + 400 + d);
      s.x += bf2f((unsigned short)u.x); s.y += bf2f((unsigned short)(u.x >> 16));
      s.z += bf2f((unsigned short)u.y); s.w += bf2f((unsigned short)(u.y >> 16));
    }
    part = tanh_fast(s.x) * qq.x + tanh_fast(s.y) * qq.y +
           tanh_fast(s.z) * qq.z + tanh_fast(s.w) * qq.w;
  }
  #pragma unroll
  for (int off = 32; off > 0; off >>= 1) part += __shfl_down(part, off, 64);
  if (lane == 0) a_out[(size_t)n * BT + b] = part;
}

// ---------------------------------------------------------------------------
// Softmax over the BATCH axis: per column n, max & 1/sum over 32768 entries.
// ---------------------------------------------------------------------------
__global__ void softmax_stats(const float* __restrict__ a,
                              float* __restrict__ rmax, float* __restrict__ rinv) {
  int n = blockIdx.x;           // 0..29
  int tid = threadIdx.x;        // 1024
  const float* col = a + (size_t)n * BT;
  float vals[32];
  float vmax = -INFINITY;
  #pragma unroll
  for (int j = 0; j < 32; ++j) {
    vals[j] = col[tid + j * 1024];
    vmax = fmaxf(vmax, vals[j]);
  }
  __shared__ float redm[16];
  __shared__ float reds[16];
  int wid = tid >> 6, lane = tid & 63;
  #pragma unroll
  for (int off = 32; off > 0; off >>= 1) vmax = fmaxf(vmax, __shfl_down(vmax, off, 64));
  if (lane == 0) redm[wid] = vmax;
  __syncthreads();
  if (tid == 0) {
    float m = redm[0];
    for (int i = 1; i < 16; ++i) m = fmaxf(m, redm[i]);
    redm[0] = m;
  }
  __syncthreads();
  float m = redm[0];
  float s = 0.f;
  #pragma unroll
  for (int j = 0; j < 32; ++j) s += __expf(vals[j] - m);
  #pragma unroll
  for (int off = 32; off > 0; off >>= 1) s += __shfl_down(s, off, 64);
  if (lane == 0) reds[wid] = s;
  __syncthreads();
  if (tid == 0) {
    float t = 0.f;
    for (int i = 0; i < 16; ++i) t += reds[i];
    rmax[n] = m;
    rinv[n] = 1.0f / t;
  }
}

// ---------------------------------------------------------------------------
// U[b, k*300+i] = sum_m alpha[b, m-k+1] * emb[tok[b,m], i]  -> bf16, stride 928
// Salpha[b] = sum_n alpha[b,n].  Block = 192 threads; tid<150 own cols 2t,2t+1.
// ---------------------------------------------------------------------------
__global__ __launch_bounds__(192) void build_U(
    const int* __restrict__ tok, const unsigned short* __restrict__ embb,
    const float* __restrict__ a, const float* __restrict__ rmax,
    const float* __restrict__ rinv, unsigned short* __restrict__ U,
    float* __restrict__ Salpha) {
  int b = blockIdx.x;
  int tid = threadIdx.x;
  __shared__ float alpha[NW];
  __shared__ int ltok[NW];
  if (tid < NW) {
    ltok[tid] = tok[b * NW + tid];
    alpha[tid] = __expf(a[(size_t)tid * BT + b] - rmax[tid]) * rinv[tid];
  }
  __syncthreads();
  if (tid == 0) {
    float s = 0.f;
    #pragma unroll
    for (int n = 0; n < NW; ++n) s += alpha[n];
    Salpha[b] = s;
  }
  unsigned short* Ub = U + (size_t)b * U_LD;
  if (tid < 150) {
    float a0 = 0.f, a1 = 0.f, a2 = 0.f;   // col x = 2*tid
    float b0 = 0.f, b1 = 0.f, b2 = 0.f;   // col y = 2*tid+1
    #pragma unroll 2
    for (int m = 0; m < NW; ++m) {
      int t = ltok[m];
      float w0 = (m + 1 < NW) ? alpha[m + 1] : 0.f;
      float w1 = alpha[m];
      float w2 = (m >= 1) ? alpha[m - 1] : 0.f;
      unsigned int u = *(const unsigned int*)(embb + (size_t)t * EMB_LD + 2 * tid);
      float x = bf2f((unsigned short)u);
      float y = bf2f((unsigned short)(u >> 16));
      a0 = fmaf(w0, x, a0); b0 = fmaf(w0, y, b0);
      a1 = fmaf(w1, x, a1); b1 = fmaf(w1, y, b1);
      a2 = fmaf(w2, x, a2); b2 = fmaf(w2, y, b2);
    }
    *(unsigned int*)(Ub + 2 * tid)       = pack2bf(a0, b0);
    *(unsigned int*)(Ub + 300 + 2 * tid) = pack2bf(a1, b1);
    *(unsigned int*)(Ub + 600 + 2 * tid) = pack2bf(a2, b2);
  } else if (tid < 164) {
    *(unsigned int*)(Ub + 900 + 2 * (tid - 150)) = 0u;   // zero pad 900..927
  }
}

// ---------------------------------------------------------------------------
extern "C" void kernel_launch(void* const* d_in, const int* in_sizes, int n_in,
                              void* d_out, int out_size, void* d_ws, size_t ws_size,
                              hipStream_t stream) {
  const int*   tok    = (const int*)d_in[0];
  const float* emb    = (const float*)d_in[1];
  const float* conv_w = (const float*)d_in[2];
  const float* conv_b = (const float*)d_in[3];
  const float* v      = (const float*)d_in[4];
  const float* vb     = (const float*)d_in[5];
  const float* q      = (const float*)d_in[6];
  float* out = (float*)d_out;

  // Workspace layout (byte offsets, all 1KB-aligned). Total ~87.5 MB.
  char* wb = (char*)d_ws;
  float* bias2           = (float*)(wb + 0);          // 200 f32
  float* rmax            = (float*)(wb + 4096);       // 30 f32
  float* rinv            = (float*)(wb + 8192);       // 30 f32
  float* Salpha          = (float*)(wb + 12288);      // 32768 f32 -> ends 143360
  float* a_ws            = (float*)(wb + 143360);     // 983040 f32 -> ends 4075520
  float* Mt              = (float*)(wb + 4076544);    // 180000 f32 -> ends 4796544
  unsigned short* embb   = (unsigned short*)(wb + 4797440);   // 10.24M bf16 -> ends 25277440
  unsigned short* MtT    = (unsigned short*)(wb + 25278464);  // 204800 bf16 -> ends 25688064
  unsigned short* WcT    = (unsigned short*)(wb + 25689088);  // 475136 bf16 -> ends 26639360
  unsigned short* big    = (unsigned short*)(wb + 26640384);  // E3 (41MB) / U (60.8MB) aliased
  unsigned short* E3 = big;
  unsigned short* U  = big;   // E3 dead after scores_kernel

  // 1. Prep: fold conv into v; transposed bf16 weights; bf16 emb
  hipLaunchKernelGGL(prep_Mt_bias, dim3(901), dim3(200), 0, stream,
                     conv_w, conv_b, v, vb, Mt, bias2);
  hipLaunchKernelGGL(conv_MtT, dim3(E3_LD), dim3(EMB_LD), 0, stream, Mt, MtT);
  hipLaunchKernelGGL(prep_WcT, dim3(WCT_ROWS), dim3(256), 0, stream, conv_w, WcT);
  hipLaunchKernelGGL(prep_emb_bf16, dim3((VOCAB * EMB_LD) / 256), dim3(256), 0, stream,
                     emb, embb);
  // 2. E3[32000,640]bf16 = embb @ MtT^T   (M=32000, N=640, K=320)
  hipLaunchKernelGGL((gemm_mfma<true>), dim3(E3_LD / 128, VOCAB / 128), dim3(256), 0, stream,
                     embb, EMB_LD, MtT, EMB_LD, (void*)E3, E3_LD, E3_LD, EMB_LD,
                     (const float*)nullptr, (const float*)nullptr);
  // 3. Attention scores a[n,b]
  hipLaunchKernelGGL(scores_kernel, dim3((BT * NW) / 4), dim3(256), 0, stream,
                     tok, E3, bias2, q, a_ws);
  // 4. Softmax-over-batch stats
  hipLaunchKernelGGL(softmax_stats, dim3(NW), dim3(1024), 0, stream, a_ws, rmax, rinv);
  // 5. U[32768,928]bf16 + Salpha
  hipLaunchKernelGGL(build_U, dim3(BT), dim3(192), 0, stream,
                     tok, embb, a_ws, rmax, rinv, U, Salpha);
  // 6. out[32768,400]f32 = U @ WcT^T + Salpha ⊗ conv_b  (N=400 guarded, K=928)
  hipLaunchKernelGGL((gemm_mfma<false>), dim3(WCT_ROWS / 128, BT / 128), dim3(256), 0, stream,
                     U, U_LD, WcT, U_LD, (void*)out, CH, CH, U_LD,
                     Salpha, conv_b);
}